// Round 3
// baseline (320.432 us; speedup 1.0000x reference)
//
#include <hip/hip_runtime.h>

typedef unsigned short u16;
typedef __attribute__((ext_vector_type(8))) short short8;   // 8 x bf16 (4 VGPRs)
typedef __attribute__((ext_vector_type(4))) float f32x4;    // MFMA accumulator

__device__ __forceinline__ u16 f2bf(float f){
  union { float f; unsigned u; } v; v.f = f;
  unsigned u = v.u;
  u += 0x7fffu + ((u >> 16) & 1u);   // RNE
  return (u16)(u >> 16);
}
__device__ __forceinline__ float bf2f(u16 h){
  union { unsigned u; float f; } v; v.u = ((unsigned)h) << 16;
  return v.f;
}

// ---------------------------------------------------------------------------
// Kernel 1: fused theta/phi/g projections.
// out[b][co][hw] = sum_k w[co][k] * x[b][k][hw] + bias[co], written as bf16.
// Tile: 64 co x 64 hw per block, micro 4x4 per thread, K-chunks of 16.
// grid: (16 hw-tiles, 3 proj * 2 co-tiles, 8 b)
// ---------------------------------------------------------------------------
__global__ __launch_bounds__(256) void proj3_kernel(
    const float* __restrict__ x,
    const float* __restrict__ tw, const float* __restrict__ tb,
    const float* __restrict__ pw, const float* __restrict__ pb,
    const float* __restrict__ gw, const float* __restrict__ gb,
    u16* __restrict__ T, u16* __restrict__ PHI, u16* __restrict__ G)
{
  const int proj = blockIdx.y >> 1;
  const int co0  = (blockIdx.y & 1) * 64;
  const float* __restrict__ W    = (proj==0) ? tw : ((proj==1) ? pw : gw);
  const float* __restrict__ bias = (proj==0) ? tb : ((proj==1) ? pb : gb);
  u16* __restrict__ out          = (proj==0) ? T  : ((proj==1) ? PHI : G);
  const int b   = blockIdx.z;
  const int hw0 = blockIdx.x * 64;
  const float* srcb = x + (size_t)b * 262144;   // 256*1024

  __shared__ float xs[16][64];
  __shared__ float wT[16][64];
  const int t = threadIdx.x;
  const int tc = t >> 4, th = t & 15;

  float acc[4][4];
  #pragma unroll
  for (int i=0;i<4;i++)
    #pragma unroll
    for (int j=0;j<4;j++) acc[i][j] = 0.f;

  for (int k0 = 0; k0 < 256; k0 += 16){
    __syncthreads();
    {
      int kk = t >> 4, col = (t & 15) * 4;
      *(float4*)&xs[kk][col] = *(const float4*)&srcb[(size_t)(k0+kk)*1024 + hw0 + col];
    }
    {
      int c = t >> 2, kk0 = (t & 3) * 4;
      float4 w4 = *(const float4*)&W[(size_t)(co0 + c) * 256 + k0 + kk0];
      wT[kk0+0][c] = w4.x; wT[kk0+1][c] = w4.y;
      wT[kk0+2][c] = w4.z; wT[kk0+3][c] = w4.w;
    }
    __syncthreads();
    #pragma unroll
    for (int kk=0;kk<16;kk++){
      float4 bv = *(const float4*)&xs[kk][th*4];
      float4 av = *(const float4*)&wT[kk][tc*4];
      float a[4]  = {av.x, av.y, av.z, av.w};
      float bb[4] = {bv.x, bv.y, bv.z, bv.w};
      #pragma unroll
      for (int i=0;i<4;i++)
        #pragma unroll
        for (int j=0;j<4;j++)
          acc[i][j] += a[i]*bb[j];
    }
  }
  #pragma unroll
  for (int i=0;i<4;i++){
    int co = co0 + tc*4 + i;
    float bs = bias[co];
    size_t base = ((size_t)b*128 + co)*1024 + hw0 + th*4;
    ushort4 u;
    u.x = f2bf(acc[i][0]+bs); u.y = f2bf(acc[i][1]+bs);
    u.z = f2bf(acc[i][2]+bs); u.w = f2bf(acc[i][3]+bs);
    *(ushort4*)&out[base] = u;
  }
}

// ---------------------------------------------------------------------------
// Kernel 2: bf16 2D transpose, dst[c][r] = src[r][c].  64x64 tiles.
// ---------------------------------------------------------------------------
__global__ __launch_bounds__(256) void transpose_bf_kernel(
    const u16* __restrict__ src, u16* __restrict__ dst, int R, int C)
{
  __shared__ u16 tile[64][72];
  const int t = threadIdx.x;
  const int c0 = blockIdx.x*64, r0 = blockIdx.y*64;
  {
    int rr = t >> 2, cs = (t & 3) * 16;
    const u16* s = src + (size_t)(r0+rr)*C + c0 + cs;
    uint4 a0 = *(const uint4*)s;
    uint4 a1 = *(const uint4*)(s+8);
    *(uint4*)&tile[rr][cs]   = a0;
    *(uint4*)&tile[rr][cs+8] = a1;
  }
  __syncthreads();
  {
    int cc = t >> 2, rs = (t & 3) * 16;
    __align__(16) u16 tmp[16];
    #pragma unroll
    for (int i=0;i<16;i++) tmp[i] = tile[rs+i][cc];
    u16* d = dst + (size_t)(c0+cc)*R + r0 + rs;
    *(uint4*)d     = *(uint4*)&tmp[0];
    *(uint4*)(d+8) = *(uint4*)&tmp[8];
  }
}

// ---------------------------------------------------------------------------
// Kernel 3: BARRIER-FREE flash attention, no-max online softmax, key-split.
// One WAVE = 32 queries x (8192/S)-key range; no __syncthreads anywhere.
// K/V fragments read directly from global (L2-resident; the 4 waves of a
// block share one key stream -> L1 reuse). P C-layout -> A-layout transform
// goes through 2 KB of wave-private, XOR-swizzled LDS (write 2-way-free,
// read contiguous-equivalent).  Partials written UNNORMALIZED as bf16.
// blockIdx: b & (S-1) = split, b >> sshift = q-group (4 q-tiles, one/wave).
// ---------------------------------------------------------------------------
__global__ __launch_bounds__(256, 4) void attn_kernel(
    const u16* __restrict__ Tq, const u16* __restrict__ Kk,
    const u16* __restrict__ Vt, u16* __restrict__ Opart,
    float* __restrict__ lpart, int sshift, int nchunk)
{
  __shared__ u16 Pall[4][1024];          // 4 waves x [32 rows][32 slots]
  const int t = threadIdx.x;
  const int wave = t >> 6, lane = t & 63;
  const int quad = lane >> 4, n16 = lane & 15;
  const int s  = blockIdx.x & ((1 << sshift) - 1);
  const int qg = blockIdx.x >> sshift;
  const int q0 = (qg*4 + wave) * 32;
  u16* Pw = Pall[wave];
  u16*   Os = Opart + (size_t)s * 1048576;   // 8192*128 bf16 per split
  float* ls = lpart + (size_t)s * 8192;

  // Q fragments: A[m=lane&15][k=quad*8+j]
  short8 qa[2][4];
  #pragma unroll
  for (int mt=0;mt<2;mt++)
    #pragma unroll
    for (int kc=0;kc<4;kc++)
      qa[mt][kc] = *(const short8*)(Tq + (size_t)(q0 + mt*16 + n16)*128 + kc*32 + quad*8);

  f32x4 o[2][8];
  float lp[2][4];
  #pragma unroll
  for (int mt=0;mt<2;mt++){
    #pragma unroll
    for (int dt=0;dt<8;dt++){ f32x4 z = {0.f,0.f,0.f,0.f}; o[mt][dt] = z; }
    #pragma unroll
    for (int r=0;r<4;r++) lp[mt][r] = 0.f;
  }

  int key0 = s * nchunk * 32;
  for (int ck=0; ck<nchunk; ck++, key0 += 32){
    // K fragments direct from global: B[n=key][k=d]
    short8 kf[2][4];
    #pragma unroll
    for (int nt=0;nt<2;nt++)
      #pragma unroll
      for (int kc=0;kc<4;kc++)
        kf[nt][kc] = *(const short8*)(Kk + (size_t)(key0 + nt*16 + n16)*128 + kc*32 + quad*8);
    // V fragments direct from global VT: B[n=d][k=key]
    short8 vf[8];
    #pragma unroll
    for (int dt=0;dt<8;dt++)
      vf[dt] = *(const short8*)(Vt + (size_t)(dt*16 + n16)*8192 + key0 + quad*8);

    // S = Q K^T (32x32 for this wave)
    f32x4 sa[2][2];
    #pragma unroll
    for (int mt=0;mt<2;mt++)
      #pragma unroll
      for (int nt=0;nt<2;nt++){
        f32x4 a = {0.f,0.f,0.f,0.f};
        #pragma unroll
        for (int kc=0;kc<4;kc++)
          a = __builtin_amdgcn_mfma_f32_16x16x32_bf16(qa[mt][kc], kf[nt][kc], a, 0, 0, 0);
        sa[mt][nt] = a;
      }

    // P = exp(S) (|S| bounded ~43, safe fp32, no max-subtract), l partials.
    // Store into wave-private LDS, XOR-swizzled:
    //   element (row,col) -> Pw[row*32 + (col ^ (((row>>2)&3)<<3))]
    #pragma unroll
    for (int mt=0;mt<2;mt++)
      #pragma unroll
      for (int nt=0;nt<2;nt++)
        #pragma unroll
        for (int r=0;r<4;r++){
          float pe = exp2f(sa[mt][nt][r] * 1.4426950408889634f);
          lp[mt][r] += pe;
          Pw[(mt*16 + quad*4 + r)*32 + ((nt*16 + n16) ^ (quad<<3))] = f2bf(pe);
        }

    // P fragments: A[m=lane&15][k=quad*8+j]; row mt*16+n16 -> group quad^(n16>>2)
    short8 pf[2];
    #pragma unroll
    for (int mt=0;mt<2;mt++)
      pf[mt] = *(const short8*)(Pw + (mt*16 + n16)*32 + ((quad ^ (n16>>2)) << 3));

    // O~ += P V
    #pragma unroll
    for (int dt=0;dt<8;dt++)
      #pragma unroll
      for (int mt=0;mt<2;mt++)
        o[mt][dt] = __builtin_amdgcn_mfma_f32_16x16x32_bf16(pf[mt], vf[dt], o[mt][dt], 0, 0, 0);
  }

  // row-sum l across the 16-lane column groups
  float l[2][4];
  #pragma unroll
  for (int mt=0;mt<2;mt++)
    #pragma unroll
    for (int r=0;r<4;r++){
      float v = lp[mt][r];
      v += __shfl_xor(v, 1, 64);
      v += __shfl_xor(v, 2, 64);
      v += __shfl_xor(v, 4, 64);
      v += __shfl_xor(v, 8, 64);
      l[mt][r] = v;
    }

  // write UNNORMALIZED O~ (bf16) and l (fp32) for this split
  #pragma unroll
  for (int mt=0;mt<2;mt++){
    #pragma unroll
    for (int dt=0;dt<8;dt++)
      #pragma unroll
      for (int r=0;r<4;r++)
        Os[(size_t)(q0 + mt*16 + quad*4 + r)*128 + dt*16 + n16] = f2bf(o[mt][dt][r]);
    if (n16 == 0)
      #pragma unroll
      for (int r=0;r<4;r++) ls[q0 + mt*16 + quad*4 + r] = l[mt][r];
  }
}

// ---------------------------------------------------------------------------
// Kernel 3b: linv[row] = 1 / sum_s lpart[s][row].   grid 32 x 256.
// ---------------------------------------------------------------------------
__global__ __launch_bounds__(256) void merge_l_kernel(
    const float* __restrict__ lpart, float* __restrict__ linv, int S)
{
  int i = blockIdx.x*256 + threadIdx.x;
  float v = 0.f;
  for (int sp=0; sp<S; sp++) v += lpart[sp*8192 + i];
  linv[i] = 1.0f / v;
}

// ---------------------------------------------------------------------------
// Kernel 4: S-way bf16 partial merge + normalize + final conv + bias + resid.
// grid: (16 hw-tiles, 4 co-tiles, 8 b)
// ---------------------------------------------------------------------------
__global__ __launch_bounds__(256) void final_kernel(
    const float* __restrict__ Ww, const float* __restrict__ Wb,
    const u16* __restrict__ Opart, const float* __restrict__ linv, int S,
    const float* __restrict__ x, float* __restrict__ outp)
{
  const int b   = blockIdx.z;
  const int co0 = blockIdx.y * 64;
  const int hw0 = blockIdx.x * 64;

  __shared__ float xs[16][64];
  __shared__ float wT[16][64];
  const int t = threadIdx.x;
  const int tc = t >> 4, th = t & 15;

  float acc[4][4];
  #pragma unroll
  for (int i=0;i<4;i++)
    #pragma unroll
    for (int j=0;j<4;j++) acc[i][j] = 0.f;

  for (int k0 = 0; k0 < 128; k0 += 16){
    __syncthreads();
    {
      int kk = t >> 4, col = (t & 15) * 4;
      size_t gflat = (size_t)b*131072 + (size_t)(k0+kk)*1024 + hw0 + col;
      int row = (int)(gflat >> 7);     // attention row of these 4 elements
      float a0=0.f, a1=0.f, a2=0.f, a3=0.f;
      for (int sp=0; sp<S; sp++){
        ushort4 v = *(const ushort4*)&Opart[(size_t)sp*1048576 + gflat];
        a0 += bf2f(v.x); a1 += bf2f(v.y); a2 += bf2f(v.z); a3 += bf2f(v.w);
      }
      float inv = linv[row];
      xs[kk][col+0] = a0*inv; xs[kk][col+1] = a1*inv;
      xs[kk][col+2] = a2*inv; xs[kk][col+3] = a3*inv;
    }
    {
      int c = t >> 2, kk0 = (t & 3) * 4;
      float4 w4 = *(const float4*)&Ww[(size_t)(co0 + c) * 128 + k0 + kk0];
      wT[kk0+0][c] = w4.x; wT[kk0+1][c] = w4.y;
      wT[kk0+2][c] = w4.z; wT[kk0+3][c] = w4.w;
    }
    __syncthreads();
    #pragma unroll
    for (int kk=0;kk<16;kk++){
      float4 bv = *(const float4*)&xs[kk][th*4];
      float4 av = *(const float4*)&wT[kk][tc*4];
      float a[4]  = {av.x, av.y, av.z, av.w};
      float bb[4] = {bv.x, bv.y, bv.z, bv.w};
      #pragma unroll
      for (int i=0;i<4;i++)
        #pragma unroll
        for (int j=0;j<4;j++)
          acc[i][j] += a[i]*bb[j];
    }
  }
  #pragma unroll
  for (int i=0;i<4;i++){
    int co = co0 + tc*4 + i;
    float bs = Wb[co];
    size_t base = ((size_t)b*256 + co)*1024 + hw0 + th*4;
    float4 xr = *(const float4*)&x[base];
    float4 r;
    r.x = acc[i][0] + bs + xr.x;
    r.y = acc[i][1] + bs + xr.y;
    r.z = acc[i][2] + bs + xr.z;
    r.w = acc[i][3] + bs + xr.w;
    *(float4*)&outp[base] = r;
  }
}

// ---------------------------------------------------------------------------
extern "C" void kernel_launch(void* const* d_in, const int* in_sizes, int n_in,
                              void* d_out, int out_size, void* d_ws, size_t ws_size,
                              hipStream_t stream)
{
  (void)in_sizes; (void)n_in; (void)out_size;
  const float* x  = (const float*)d_in[0];
  const float* tw = (const float*)d_in[1];
  const float* tb = (const float*)d_in[2];
  const float* pw = (const float*)d_in[3];
  const float* pb = (const float*)d_in[4];
  const float* gw = (const float*)d_in[5];
  const float* gb = (const float*)d_in[6];
  const float* Ww = (const float*)d_in[7];
  const float* Wb = (const float*)d_in[8];
  float* outp = (float*)d_out;

  char* ws = (char*)d_ws;
  const size_t MB = 1u << 20;
  u16*   Tbf   = (u16*)(ws);            // 2 MB  theta bf16 [8192][128]
  u16*   PHIbf = (u16*)(ws + 2*MB);     // 2 MB  phi   bf16 [128][8192]
  u16*   Gbf   = (u16*)(ws + 4*MB);     // 2 MB  g     bf16 [8192][128]
  u16*   Kbf   = (u16*)(ws + 6*MB);     // 2 MB  K = phi^T  [8192][128]
  u16*   VTbf  = (u16*)(ws + 8*MB);     // 2 MB  VT = g^T   [128][8192]

  // Key-split: S=16 if workspace allows, else S=8 (guaranteed: R1 proved
  // ws_size >= 27.39 MB). Partials are bf16 at [10MB, 10+2S MB);
  // lpart/linv live in the PHI/G region, dead by the time attn runs.
  int S, sshift;
  if (ws_size >= 10*MB + 32*MB) { S = 16; sshift = 4; }
  else                          { S = 8;  sshift = 3; }
  u16*   Opart = (u16*)(ws + 10*MB);                 // S x 2 MB bf16
  float* lpart = (float*)(ws + 2*MB);                // S x 32 KB
  float* linv  = (float*)(ws + 2*MB + 512*1024);     // 32 KB

  proj3_kernel<<<dim3(16, 6, 8), 256, 0, stream>>>(x, tw, tb, pw, pb, gw, gb,
                                                   Tbf, PHIbf, Gbf);
  transpose_bf_kernel<<<dim3(128, 2), 256, 0, stream>>>(PHIbf, Kbf, 128, 8192);
  transpose_bf_kernel<<<dim3(2, 128), 256, 0, stream>>>(Gbf, VTbf, 8192, 128);
  attn_kernel<<<dim3(64*S), 256, 0, stream>>>(Tbf, Kbf, VTbf, Opart, lpart,
                                              sshift, 256/S);
  merge_l_kernel<<<dim3(32), 256, 0, stream>>>(lpart, linv, S);
  final_kernel<<<dim3(16, 4, 8), 256, 0, stream>>>(Ww, Wb, Opart, linv, S, x, outp);
}

// Round 5
// 199.684 us; speedup vs baseline: 1.6047x; 1.6047x over previous
//
#include <hip/hip_runtime.h>

typedef unsigned short u16;
typedef __attribute__((ext_vector_type(8))) short short8;   // 8 x bf16 (4 VGPRs)
typedef __attribute__((ext_vector_type(4))) float f32x4;    // MFMA accumulator

__device__ __forceinline__ u16 f2bf(float f){
  union { float f; unsigned u; } v; v.f = f;
  unsigned u = v.u;
  u += 0x7fffu + ((u >> 16) & 1u);   // RNE
  return (u16)(u >> 16);
}

// ---------------------------------------------------------------------------
// Kernel 1: fused theta/phi/g projections (fp32 vector GEMM, bf16 out).
// grid: (16 hw-tiles, 3 proj * 2 co-tiles, 8 b)
// ---------------------------------------------------------------------------
__global__ __launch_bounds__(256) void proj3_kernel(
    const float* __restrict__ x,
    const float* __restrict__ tw, const float* __restrict__ tb,
    const float* __restrict__ pw, const float* __restrict__ pb,
    const float* __restrict__ gw, const float* __restrict__ gb,
    u16* __restrict__ T, u16* __restrict__ PHI, u16* __restrict__ G)
{
  const int proj = blockIdx.y >> 1;
  const int co0  = (blockIdx.y & 1) * 64;
  const float* __restrict__ W    = (proj==0) ? tw : ((proj==1) ? pw : gw);
  const float* __restrict__ bias = (proj==0) ? tb : ((proj==1) ? pb : gb);
  u16* __restrict__ out          = (proj==0) ? T  : ((proj==1) ? PHI : G);
  const int b   = blockIdx.z;
  const int hw0 = blockIdx.x * 64;
  const float* srcb = x + (size_t)b * 262144;   // 256*1024

  __shared__ float xs[16][64];
  __shared__ float wT[16][64];
  const int t = threadIdx.x;
  const int tc = t >> 4, th = t & 15;

  float acc[4][4];
  #pragma unroll
  for (int i=0;i<4;i++)
    #pragma unroll
    for (int j=0;j<4;j++) acc[i][j] = 0.f;

  for (int k0 = 0; k0 < 256; k0 += 16){
    __syncthreads();
    {
      int kk = t >> 4, col = (t & 15) * 4;
      *(float4*)&xs[kk][col] = *(const float4*)&srcb[(size_t)(k0+kk)*1024 + hw0 + col];
    }
    {
      int c = t >> 2, kk0 = (t & 3) * 4;
      float4 w4 = *(const float4*)&W[(size_t)(co0 + c) * 256 + k0 + kk0];
      wT[kk0+0][c] = w4.x; wT[kk0+1][c] = w4.y;
      wT[kk0+2][c] = w4.z; wT[kk0+3][c] = w4.w;
    }
    __syncthreads();
    #pragma unroll
    for (int kk=0;kk<16;kk++){
      float4 bv = *(const float4*)&xs[kk][th*4];
      float4 av = *(const float4*)&wT[kk][tc*4];
      float a[4]  = {av.x, av.y, av.z, av.w};
      float bb[4] = {bv.x, bv.y, bv.z, bv.w};
      #pragma unroll
      for (int i=0;i<4;i++)
        #pragma unroll
        for (int j=0;j<4;j++)
          acc[i][j] += a[i]*bb[j];
    }
  }
  #pragma unroll
  for (int i=0;i<4;i++){
    int co = co0 + tc*4 + i;
    float bs = bias[co];
    size_t base = ((size_t)b*128 + co)*1024 + hw0 + th*4;
    ushort4 u;
    u.x = f2bf(acc[i][0]+bs); u.y = f2bf(acc[i][1]+bs);
    u.z = f2bf(acc[i][2]+bs); u.w = f2bf(acc[i][3]+bs);
    *(ushort4*)&out[base] = u;
  }
}

// ---------------------------------------------------------------------------
// Kernel 2: bf16 2D transpose, dst[c][r] = src[r][c].  64x64 tiles.
// ---------------------------------------------------------------------------
__global__ __launch_bounds__(256) void transpose_bf_kernel(
    const u16* __restrict__ src, u16* __restrict__ dst, int R, int C)
{
  __shared__ u16 tile[64][72];
  const int t = threadIdx.x;
  const int c0 = blockIdx.x*64, r0 = blockIdx.y*64;
  {
    int rr = t >> 2, cs = (t & 3) * 16;
    const u16* s = src + (size_t)(r0+rr)*C + c0 + cs;
    uint4 a0 = *(const uint4*)s;
    uint4 a1 = *(const uint4*)(s+8);
    *(uint4*)&tile[rr][cs]   = a0;
    *(uint4*)&tile[rr][cs+8] = a1;
  }
  __syncthreads();
  {
    int cc = t >> 2, rs = (t & 3) * 16;
    __align__(16) u16 tmp[16];
    #pragma unroll
    for (int i=0;i<16;i++) tmp[i] = tile[rs+i][cc];
    u16* d = dst + (size_t)(c0+cc)*R + r0 + rs;
    *(uint4*)d     = *(uint4*)&tmp[0];
    *(uint4*)(d+8) = *(uint4*)&tmp[8];
  }
}

// ---------------------------------------------------------------------------
// Kernel 3: flash attention, LDS-staged K AND V, 64-key tiles, key-split.
// Block = 4 waves; wave w owns queries [qg*128 + w*32, +32); ALL waves
// process the full 64-key tile (staging amortized 4x vs R1).
// No-max online softmax (|S|<=~43, exp safe in fp32); partials unnormalized.
// grid: (S, 64 q-groups). Split s handles tiles [ts, ts+ntil) of 128
// 64-key tiles (uneven ok: partials are plain sums).
// Partial O~ stored fp32 in MFMA C-layout (16-lane 64B segments — coalesced,
// no write amplification, no LDS round-trip: the R1-proven store pattern).
// ---------------------------------------------------------------------------
__global__ __launch_bounds__(256, 3) void attn_kernel(
    const u16* __restrict__ Tq, const u16* __restrict__ Kk,
    const u16* __restrict__ Vt, float* __restrict__ Opart,
    float* __restrict__ lpart, int base, int rem)
{
  __shared__ __align__(16) u16 Ks[64][136];    // 17408 B (+8 pad)
  __shared__ __align__(16) u16 Vs[128][72];    // 18432 B (+8 pad)
  __shared__ __align__(16) u16 Pall[4][2048];  // 4 KB per wave

  const int t = threadIdx.x;
  const int wave = t >> 6, lane = t & 63;
  const int quad = lane >> 4, n16 = lane & 15;
  const int s  = blockIdx.x;
  const int qg = blockIdx.y;
  const int q0 = qg*128 + wave*32;
  u16* Pw = Pall[wave];
  float* Os = Opart + (size_t)s * 1048576;     // 8192*128 fp32 per split
  float* ls = lpart + (size_t)s * 8192;

  const int ts   = s*base + (s < rem ? s : rem);
  const int ntil = base + (s < rem ? 1 : 0);

  // Q fragments: A[m=lane&15][k=quad*8+j]
  short8 qa[2][4];
  #pragma unroll
  for (int mt=0;mt<2;mt++)
    #pragma unroll
    for (int kc=0;kc<4;kc++)
      qa[mt][kc] = *(const short8*)(Tq + (size_t)(q0 + mt*16 + n16)*128 + kc*32 + quad*8);

  f32x4 o[2][8];
  float lp[2][4];
  #pragma unroll
  for (int mt=0;mt<2;mt++){
    #pragma unroll
    for (int dt=0;dt<8;dt++){ f32x4 z = {0.f,0.f,0.f,0.f}; o[mt][dt] = z; }
    #pragma unroll
    for (int r=0;r<4;r++) lp[mt][r] = 0.f;
  }

  const int krow = t >> 2, kcs = (t & 3) * 32;   // K stage: 64 rows x 128 u16
  const int vrow = t >> 1, vcs = (t & 1) * 32;   // V stage: 128 rows x 64 u16

  for (int kt = ts; kt < ts + ntil; kt++){
    const int key0 = kt * 64;
    __syncthreads();
    #pragma unroll
    for (int i=0;i<4;i++)
      *(uint4*)&Ks[krow][kcs + i*8] =
        *(const uint4*)(Kk + (size_t)(key0 + krow)*128 + kcs + i*8);
    #pragma unroll
    for (int i=0;i<4;i++)
      *(uint4*)&Vs[vrow][vcs + i*8] =
        *(const uint4*)(Vt + (size_t)vrow*8192 + key0 + vcs + i*8);
    __syncthreads();

    // QK^T + exp, one 16-key column block (nt) at a time to bound registers
    #pragma unroll
    for (int nt=0; nt<4; nt++){
      short8 kf[4];
      #pragma unroll
      for (int kc=0;kc<4;kc++)
        kf[kc] = *(const short8*)&Ks[nt*16 + n16][kc*32 + quad*8];
      f32x4 s0 = {0.f,0.f,0.f,0.f}, s1 = {0.f,0.f,0.f,0.f};
      #pragma unroll
      for (int kc=0;kc<4;kc++){
        s0 = __builtin_amdgcn_mfma_f32_16x16x32_bf16(qa[0][kc], kf[kc], s0, 0, 0, 0);
        s1 = __builtin_amdgcn_mfma_f32_16x16x32_bf16(qa[1][kc], kf[kc], s1, 0, 0, 0);
      }
      #pragma unroll
      for (int r=0;r<4;r++){
        float p0 = exp2f(s0[r] * 1.4426950408889634f);
        lp[0][r] += p0;
        Pw[(quad*4 + r)*64      + ((nt*16 + n16) ^ (quad<<3))] = f2bf(p0);
        float p1 = exp2f(s1[r] * 1.4426950408889634f);
        lp[1][r] += p1;
        Pw[(16 + quad*4 + r)*64 + ((nt*16 + n16) ^ (quad<<3))] = f2bf(p1);
      }
    }

    // drain DS queue: P-writes (cross-lane producers) must complete before
    // the cross-lane P-fragment reads below.  lgkmcnt(0), vm/exp unconstrained.
    __builtin_amdgcn_s_waitcnt(0xC07F);

    // O~ += P V, per 32-key half (kb)
    #pragma unroll
    for (int kb=0; kb<2; kb++){
      const int psw = kb*32 + ((quad ^ (n16>>2)) << 3);
      short8 pf0 = *(const short8*)(Pw + n16*64        + psw);
      short8 pf1 = *(const short8*)(Pw + (16 + n16)*64 + psw);
      #pragma unroll
      for (int dt=0; dt<8; dt++){
        short8 vfd = *(const short8*)&Vs[dt*16 + n16][kb*32 + quad*8];
        o[0][dt] = __builtin_amdgcn_mfma_f32_16x16x32_bf16(pf0, vfd, o[0][dt], 0, 0, 0);
        o[1][dt] = __builtin_amdgcn_mfma_f32_16x16x32_bf16(pf1, vfd, o[1][dt], 0, 0, 0);
      }
    }
  }

  // row-sum l across the 16-lane column groups
  float l[2][4];
  #pragma unroll
  for (int mt=0;mt<2;mt++)
    #pragma unroll
    for (int r=0;r<4;r++){
      float v = lp[mt][r];
      v += __shfl_xor(v, 1, 64);
      v += __shfl_xor(v, 2, 64);
      v += __shfl_xor(v, 4, 64);
      v += __shfl_xor(v, 8, 64);
      l[mt][r] = v;
    }

  __syncthreads();   // uniform arrival; quiesce before epilogue

  // Epilogue: UNNORMALIZED fp32 partials in C-layout, straight from regs.
  // Per store: each quad's 16 lanes cover 64B contiguous — fully coalesced.
  #pragma unroll
  for (int mt=0;mt<2;mt++){
    #pragma unroll
    for (int dt=0;dt<8;dt++)
      #pragma unroll
      for (int r=0;r<4;r++)
        Os[(size_t)(q0 + mt*16 + quad*4 + r)*128 + dt*16 + n16] = o[mt][dt][r];
    if (n16 == 0)
      #pragma unroll
      for (int r=0;r<4;r++) ls[q0 + mt*16 + quad*4 + r] = l[mt][r];
  }
}

// ---------------------------------------------------------------------------
// Kernel 3b: linv[row] = 1 / sum_s lpart[s][row].   grid 32 x 256.
// ---------------------------------------------------------------------------
__global__ __launch_bounds__(256) void merge_l_kernel(
    const float* __restrict__ lpart, float* __restrict__ linv, int S)
{
  int i = blockIdx.x*256 + threadIdx.x;
  float v = 0.f;
  for (int sp=0; sp<S; sp++) v += lpart[sp*8192 + i];
  linv[i] = 1.0f / v;
}

// ---------------------------------------------------------------------------
// Kernel 4: S-way fp32 partial merge + normalize + final conv + bias + resid.
// grid: (16 hw-tiles, 4 co-tiles, 8 b)
// ---------------------------------------------------------------------------
__global__ __launch_bounds__(256) void final_kernel(
    const float* __restrict__ Ww, const float* __restrict__ Wb,
    const float* __restrict__ Opart, const float* __restrict__ linv, int S,
    const float* __restrict__ x, float* __restrict__ outp)
{
  const int b   = blockIdx.z;
  const int co0 = blockIdx.y * 64;
  const int hw0 = blockIdx.x * 64;

  __shared__ float xs[16][64];
  __shared__ float wT[16][64];
  const int t = threadIdx.x;
  const int tc = t >> 4, th = t & 15;

  float acc[4][4];
  #pragma unroll
  for (int i=0;i<4;i++)
    #pragma unroll
    for (int j=0;j<4;j++) acc[i][j] = 0.f;

  for (int k0 = 0; k0 < 128; k0 += 16){
    __syncthreads();
    {
      int kk = t >> 4, col = (t & 15) * 4;
      size_t gflat = (size_t)b*131072 + (size_t)(k0+kk)*1024 + hw0 + col;
      int row = (int)(gflat >> 7);     // attention row of these 4 elements
      float a0=0.f, a1=0.f, a2=0.f, a3=0.f;
      for (int sp=0; sp<S; sp++){
        float4 v = *(const float4*)&Opart[(size_t)sp*1048576 + gflat];
        a0 += v.x; a1 += v.y; a2 += v.z; a3 += v.w;
      }
      float inv = linv[row];
      xs[kk][col+0] = a0*inv; xs[kk][col+1] = a1*inv;
      xs[kk][col+2] = a2*inv; xs[kk][col+3] = a3*inv;
    }
    {
      int c = t >> 2, kk0 = (t & 3) * 4;
      float4 w4 = *(const float4*)&Ww[(size_t)(co0 + c) * 128 + k0 + kk0];
      wT[kk0+0][c] = w4.x; wT[kk0+1][c] = w4.y;
      wT[kk0+2][c] = w4.z; wT[kk0+3][c] = w4.w;
    }
    __syncthreads();
    #pragma unroll
    for (int kk=0;kk<16;kk++){
      float4 bv = *(const float4*)&xs[kk][th*4];
      float4 av = *(const float4*)&wT[kk][tc*4];
      float a[4]  = {av.x, av.y, av.z, av.w};
      float bb[4] = {bv.x, bv.y, bv.z, bv.w};
      #pragma unroll
      for (int i=0;i<4;i++)
        #pragma unroll
        for (int j=0;j<4;j++)
          acc[i][j] += a[i]*bb[j];
    }
  }
  #pragma unroll
  for (int i=0;i<4;i++){
    int co = co0 + tc*4 + i;
    float bs = Wb[co];
    size_t base = ((size_t)b*256 + co)*1024 + hw0 + th*4;
    float4 xr = *(const float4*)&x[base];
    float4 r;
    r.x = acc[i][0] + bs + xr.x;
    r.y = acc[i][1] + bs + xr.y;
    r.z = acc[i][2] + bs + xr.z;
    r.w = acc[i][3] + bs + xr.w;
    *(float4*)&outp[base] = r;
  }
}

// ---------------------------------------------------------------------------
extern "C" void kernel_launch(void* const* d_in, const int* in_sizes, int n_in,
                              void* d_out, int out_size, void* d_ws, size_t ws_size,
                              hipStream_t stream)
{
  (void)in_sizes; (void)n_in; (void)out_size;
  const float* x  = (const float*)d_in[0];
  const float* tw = (const float*)d_in[1];
  const float* tb = (const float*)d_in[2];
  const float* pw = (const float*)d_in[3];
  const float* pb = (const float*)d_in[4];
  const float* gw = (const float*)d_in[5];
  const float* gb = (const float*)d_in[6];
  const float* Ww = (const float*)d_in[7];
  const float* Wb = (const float*)d_in[8];
  float* outp = (float*)d_out;

  char* ws = (char*)d_ws;
  const size_t MB = 1u << 20;
  u16*   Tbf   = (u16*)(ws);            // 2 MB  theta bf16 [8192][128] (flat)
  u16*   PHIbf = (u16*)(ws + 2*MB);     // 2 MB  phi   bf16 [128][8192] (flat)
  u16*   Gbf   = (u16*)(ws + 4*MB);     // 2 MB  g     bf16 [8192][128] (flat)
  u16*   Kbf   = (u16*)(ws + 6*MB);     // 2 MB  K = phi^T  [8192][128]
  u16*   VTbf  = (u16*)(ws + 8*MB);     // 2 MB  VT = g^T   [128][8192]

  // Key-split cascade by workspace (fp32 partials, S x 4 MB at ws+10MB).
  // Floor S=4 needs 26 MB — proven available by R1's passing run.
  const int TILES = 128;                // 64-key tiles
  int S;
  if      (ws_size >= 10*MB + 48*MB + 1*MB) S = 12;
  else if (ws_size >= 10*MB + 40*MB + 1*MB) S = 10;
  else if (ws_size >= 10*MB + 32*MB + 1*MB) S = 8;
  else if (ws_size >= 10*MB + 24*MB + 1*MB) S = 6;
  else                                      S = 4;
  int base = TILES / S, rem = TILES % S;
  float* Opart = (float*)(ws + 10*MB);               // S x 4 MB fp32
  float* lpart = (float*)(ws + 2*MB);                // S x 32 KB (PHI dead)
  float* linv  = (float*)(ws + 2*MB + 512*1024);     // 32 KB

  proj3_kernel<<<dim3(16, 6, 8), 256, 0, stream>>>(x, tw, tb, pw, pb, gw, gb,
                                                   Tbf, PHIbf, Gbf);
  transpose_bf_kernel<<<dim3(128, 2), 256, 0, stream>>>(PHIbf, Kbf, 128, 8192);
  transpose_bf_kernel<<<dim3(2, 128), 256, 0, stream>>>(Gbf, VTbf, 8192, 128);
  attn_kernel<<<dim3(S, 64), 256, 0, stream>>>(Tbf, Kbf, VTbf, Opart, lpart,
                                               base, rem);
  merge_l_kernel<<<dim3(32), 256, 0, stream>>>(lpart, linv, S);
  final_kernel<<<dim3(16, 4, 8), 256, 0, stream>>>(Ww, Wb, Opart, linv, S, x, outp);
}